// Round 1
// baseline (400.497 us; speedup 1.0000x reference)
//
#include <hip/hip_runtime.h>

#define TT 52          // tag count incl START/STOP
#define NT 50          // normal tags
#define START_TAG 50
#define STOP_TAG 51
#define BB 1024
#define SS 512
#define BPSTR 64       // LDS backpointer row stride (bytes)

__global__ __launch_bounds__(64, 1) void crf_viterbi(
    const float* __restrict__ feats,   // [B,S,T]
    const void*  __restrict__ mask,    // [B,S] dtype unknown (bool8/f32/i32/i64)
    const float* __restrict__ trans,   // [T,T]
    int* __restrict__ out)             // [B,S]
{
    __shared__ float alpha_sh[2][64];
    __shared__ unsigned char bp_sh[SS * BPSTR];   // 32 KB

    const int b = blockIdx.x;
    const int j = threadIdx.x;            // tag owned by this lane (j<50 real)
    const int jc = j < NT ? j : NT - 1;   // clamped for safe loads

    // ---- sequence length from prefix mask (dtype auto-detect) ----
    int cnt = 0;
    {
        const unsigned* w = (const unsigned*)mask;
        unsigned w0 = w[0];
        unsigned w1 = w[1];
        if (w0 == 0x01010101u) {                       // bool / uint8
            const unsigned char* m = (const unsigned char*)mask + (size_t)b * SS;
            for (int k = j; k < SS; k += 64) cnt += (m[k] != 0);
        } else if (w0 == 0x3f800000u) {                // float32
            const float* m = (const float*)mask + (size_t)b * SS;
            for (int k = j; k < SS; k += 64) cnt += (m[k] != 0.f);
        } else if (w1 == 1u) {                         // int32
            const int* m = (const int*)mask + (size_t)b * SS;
            for (int k = j; k < SS; k += 64) cnt += (m[k] != 0);
        } else {                                       // int64
            const long long* m = (const long long*)mask + (size_t)b * SS;
            for (int k = j; k < SS; k += 64) cnt += (m[k] != 0);
        }
        for (int off = 32; off; off >>= 1) cnt += __shfl_xor(cnt, off, 64);
    }
    const int len = cnt > 0 ? cnt : 1;

    // ---- transition column trans[0..49][j] into registers ----
    float tt[NT];
#pragma unroll
    for (int i = 0; i < NT; ++i) tt[i] = trans[i * TT + j];  // j<=63: max idx 49*52+63=2611 < 2704

    // ---- init alpha (pos 0) ----
    const float* fp = feats + ((size_t)b * SS) * TT + jc;
    float alpha = trans[START_TAG * TT + jc] + fp[0];
    float fnext = fp[TT];   // feats for pos=1 (S>=2 always)

    // ---- forward DP ----
    for (int pos = 1; pos < len; ++pos) {
        const float f = fnext;
        if (pos + 1 < SS) fnext = fp[(size_t)(pos + 1) * TT];

        alpha_sh[pos & 1][j] = alpha;
        __syncthreads();
        const float4* a4p = (const float4*)alpha_sh[pos & 1];

        float best0 = -3.0e38f, best1 = -3.0e38f, best2 = -3.0e38f, best3 = -3.0e38f;
        int bi0 = 0, bi1 = 1, bi2 = 2, bi3 = 3;
#pragma unroll
        for (int ii = 0; ii < 13; ++ii) {
            float4 a4 = a4p[ii];
            {
                float s = a4.x + tt[4 * ii + 0];
                if (s > best0) { best0 = s; bi0 = 4 * ii + 0; }
            }
            if (4 * ii + 1 < NT) {
                float s = a4.y + tt[4 * ii + 1];
                if (s > best1) { best1 = s; bi1 = 4 * ii + 1; }
            }
            if (4 * ii + 2 < NT) {
                float s = a4.z + tt[4 * ii + 2];
                if (s > best2) { best2 = s; bi2 = 4 * ii + 2; }
            }
            if (4 * ii + 3 < NT) {
                float s = a4.w + tt[4 * ii + 3];
                if (s > best3) { best3 = s; bi3 = 4 * ii + 3; }
            }
        }
        // merge 4 chains with first-index tie-break (matches jnp.argmax)
        float bv = best0; int bidx = bi0;
        if (best1 > bv || (best1 == bv && bi1 < bidx)) { bv = best1; bidx = bi1; }
        if (best2 > bv || (best2 == bv && bi2 < bidx)) { bv = best2; bidx = bi2; }
        if (best3 > bv || (best3 == bv && bi3 < bidx)) { bv = best3; bidx = bi3; }

        alpha = bv + f;
        bp_sh[pos * BPSTR + j] = (unsigned char)bidx;
    }

    // ---- best last tag: argmax_j(alpha[j] + trans[j,STOP]) ----
    float v = alpha + trans[jc * TT + STOP_TAG];
    if (j >= NT) v = -3.0e38f;
    int idx = j < NT ? j : 0;
    for (int off = 32; off; off >>= 1) {
        float vo = __shfl_xor(v, off, 64);
        int   io = __shfl_xor(idx, off, 64);
        if (vo > v || (vo == v && io < idx)) { v = vo; idx = io; }
    }

    __syncthreads();  // ensure all bp writes visible before traceback

    // ---- traceback (LDS chase, wave-uniform) ----
    int ptr = idx;
    int* ob = out + (size_t)b * SS;
    for (int pos = len - 1; pos >= 1; --pos) {
        if (j == 0) ob[pos] = ptr;
        ptr = (int)bp_sh[pos * BPSTR + ptr];
    }
    if (j == 0) ob[0] = ptr;

    // ---- zero-fill positions >= len ----
    for (int p = len + j; p < SS; p += 64) ob[p] = 0;
}

extern "C" void kernel_launch(void* const* d_in, const int* in_sizes, int n_in,
                              void* d_out, int out_size, void* d_ws, size_t ws_size,
                              hipStream_t stream) {
    const float* feats = (const float*)d_in[0];
    const void*  mask  = d_in[1];
    // d_in[2] = tags, unused by Viterbi decode
    const float* trans = (const float*)d_in[3];
    int* out = (int*)d_out;

    crf_viterbi<<<dim3(BB), dim3(64), 0, stream>>>(feats, mask, trans, out);
}

// Round 2
// 330.420 us; speedup vs baseline: 1.2121x; 1.2121x over previous
//
#include <hip/hip_runtime.h>

#define TT 52          // tag count incl START/STOP
#define NT 50          // normal tags
#define START_TAG 50
#define STOP_TAG 51
#define BB 1024
#define SS 512
#define BPSTR 64       // LDS backpointer row stride (bytes)

__global__ __launch_bounds__(64, 1) void crf_viterbi(
    const float* __restrict__ feats,   // [B,S,T]
    const void*  __restrict__ mask,    // [B,S] dtype unknown (bool8/f32/i32/i64)
    const float* __restrict__ trans,   // [T,T]
    int* __restrict__ out)             // [B,S]
{
    __shared__ unsigned char bp_sh[SS * BPSTR];   // 32 KB backpointers

    const int b = blockIdx.x;
    const int j = threadIdx.x;            // tag owned by this lane (j<50 real)
    const int jc = j < NT ? j : NT - 1;   // clamped for safe loads

    // ---- sequence length from prefix mask (dtype auto-detect) ----
    int cnt = 0;
    {
        const unsigned* w = (const unsigned*)mask;
        unsigned w0 = w[0];
        unsigned w1 = w[1];
        if (w0 == 0x01010101u) {                       // bool / uint8
            const unsigned char* m = (const unsigned char*)mask + (size_t)b * SS;
            for (int k = j; k < SS; k += 64) cnt += (m[k] != 0);
        } else if (w0 == 0x3f800000u) {                // float32
            const float* m = (const float*)mask + (size_t)b * SS;
            for (int k = j; k < SS; k += 64) cnt += (m[k] != 0.f);
        } else if (w1 == 1u) {                         // int32
            const int* m = (const int*)mask + (size_t)b * SS;
            for (int k = j; k < SS; k += 64) cnt += (m[k] != 0);
        } else {                                       // int64
            const long long* m = (const long long*)mask + (size_t)b * SS;
            for (int k = j; k < SS; k += 64) cnt += (m[k] != 0);
        }
        for (int off = 32; off; off >>= 1) cnt += __shfl_xor(cnt, off, 64);
    }
    const int len = cnt > 0 ? cnt : 1;

    // ---- transition column trans[0..49][j] into registers ----
    float tt[NT];
#pragma unroll
    for (int i = 0; i < NT; ++i) tt[i] = trans[i * TT + j];  // j<=63: max idx 49*52+63=2611 < 2704

    // ---- init alpha (pos 0) ----
    const float* fp = feats + ((size_t)b * SS) * TT + jc;
    float alpha = trans[START_TAG * TT + jc] + fp[0];
    float fnext = fp[TT];   // feats for pos=1 (S>=2 always)

    // ---- forward DP (alpha broadcast via readlane, no LDS round trip) ----
    for (int pos = 1; pos < len; ++pos) {
        const float f = fnext;
        {
            int np = pos + 1 < SS ? pos + 1 : SS - 1;
            fnext = fp[(size_t)np * TT];
        }

        float best[4] = { -3.0e38f, -3.0e38f, -3.0e38f, -3.0e38f };
        int   bidx[4] = { 0, 0, 0, 0 };
        const int abits = __builtin_bit_cast(int, alpha);
#pragma unroll
        for (int i = 0; i < NT; ++i) {
            int ab = __builtin_amdgcn_readlane(abits, i);   // broadcast alpha[i]
            float s = __builtin_bit_cast(float, ab) + tt[i];
            const int c = i & 3;                            // 4 independent chains
            if (s > best[c]) { best[c] = s; bidx[c] = i; }
        }
        // merge 4 chains with first-index tie-break (matches jnp.argmax)
        float bv = best[0]; int bi = bidx[0];
        if (best[1] > bv || (best[1] == bv && bidx[1] < bi)) { bv = best[1]; bi = bidx[1]; }
        if (best[2] > bv || (best[2] == bv && bidx[2] < bi)) { bv = best[2]; bi = bidx[2]; }
        if (best[3] > bv || (best[3] == bv && bidx[3] < bi)) { bv = best[3]; bi = bidx[3]; }

        alpha = bv + f;
        bp_sh[pos * BPSTR + j] = (unsigned char)bi;
    }

    // ---- best last tag: argmax_j(alpha[j] + trans[j,STOP]) ----
    float v = alpha + trans[jc * TT + STOP_TAG];
    if (j >= NT) v = -3.0e38f;
    int idx = j < NT ? j : 0;
    for (int off = 32; off; off >>= 1) {
        float vo = __shfl_xor(v, off, 64);
        int   io = __shfl_xor(idx, off, 64);
        if (vo > v || (vo == v && io < idx)) { v = vo; idx = io; }
    }

    __syncthreads();  // drain bp LDS writes before traceback reads

    // ---- traceback (LDS chase, wave-uniform) ----
    int ptr = idx;
    int* ob = out + (size_t)b * SS;
    for (int pos = len - 1; pos >= 1; --pos) {
        if (j == 0) ob[pos] = ptr;
        ptr = (int)bp_sh[pos * BPSTR + ptr];
    }
    if (j == 0) ob[0] = ptr;

    // ---- zero-fill positions >= len ----
    for (int p = len + j; p < SS; p += 64) ob[p] = 0;
}

extern "C" void kernel_launch(void* const* d_in, const int* in_sizes, int n_in,
                              void* d_out, int out_size, void* d_ws, size_t ws_size,
                              hipStream_t stream) {
    const float* feats = (const float*)d_in[0];
    const void*  mask  = d_in[1];
    // d_in[2] = tags, unused by Viterbi decode
    const float* trans = (const float*)d_in[3];
    int* out = (int*)d_out;

    crf_viterbi<<<dim3(BB), dim3(64), 0, stream>>>(feats, mask, trans, out);
}

// Round 3
// 264.616 us; speedup vs baseline: 1.5135x; 1.2487x over previous
//
#include <hip/hip_runtime.h>

#define TT 52          // tag count incl START/STOP
#define NT 50          // normal tags
#define START_TAG 50
#define STOP_TAG 51
#define BB 1024
#define SS 512
#define BPSTR 64       // fallback kernel LDS bp row stride

__device__ __forceinline__ int seq_len(const void* mask, int b, int j) {
    int cnt = 0;
    const unsigned* w = (const unsigned*)mask;
    unsigned w0 = w[0];
    unsigned w1 = w[1];
    if (w0 == 0x01010101u) {                       // bool / uint8
        const unsigned char* m = (const unsigned char*)mask + (size_t)b * SS;
        for (int k = j; k < SS; k += 64) cnt += (m[k] != 0);
    } else if (w0 == 0x3f800000u) {                // float32
        const float* m = (const float*)mask + (size_t)b * SS;
        for (int k = j; k < SS; k += 64) cnt += (m[k] != 0.f);
    } else if (w1 == 1u) {                         // int32
        const int* m = (const int*)mask + (size_t)b * SS;
        for (int k = j; k < SS; k += 64) cnt += (m[k] != 0);
    } else {                                       // int64
        const long long* m = (const long long*)mask + (size_t)b * SS;
        for (int k = j; k < SS; k += 64) cnt += (m[k] != 0);
    }
    for (int off = 32; off; off >>= 1) cnt += __shfl_xor(cnt, off, 64);
    return cnt > 0 ? cnt : 1;
}

// ---------------- fast kernel: no per-step argmax; value-match traceback ----
__global__ __launch_bounds__(64, 1) void crf_viterbi_fast(
    const float* __restrict__ feats,   // [B,S,T]
    const void*  __restrict__ mask,    // [B,S]
    const float* __restrict__ trans,   // [T,T]
    float* __restrict__ ws,            // [B,S,64] bv history (128 MiB)
    int* __restrict__ out)             // [B,S]
{
    __shared__ float trans_lds[64 * 53];   // [row i][col c], 53-padded (conflict-free col reads)

    const int b = blockIdx.x;
    const int j = threadIdx.x;
    const int jc = j < NT ? j : NT - 1;
    const int jr = j * 53;

    // stage trans rows into LDS; rows >= NT get -inf sentinel
    for (int k = j; k < 64 * 53; k += 64) {
        int r = k / 53, c = k - r * 53;
        float v = -3.0e38f;
        if (r < NT && c < TT) v = trans[r * TT + c];
        trans_lds[k] = v;
    }

    const int len = seq_len(mask, b, j);

    // transition column trans[0..49][j] into registers
    float tt[NT];
#pragma unroll
    for (int i = 0; i < NT; ++i) tt[i] = trans[i * TT + j];

    // init (pos 0): alpha0 = bv0 + f0 with bv0 = trans[START][j]
    const float* fp = feats + ((size_t)b * SS) * TT + jc;
    float* wsb = ws + ((size_t)b * SS) * 64 + j;
    const float bv0 = trans[START_TAG * TT + jc];
    float alpha = bv0 + fp[0];
    wsb[0] = bv0;
    float fnext = fp[TT];

    // ---- forward: max only, no argmax ----
    for (int pos = 1; pos < len; ++pos) {
        const float f = fnext;
        { int np = pos + 1 < SS ? pos + 1 : SS - 1; fnext = fp[(size_t)np * TT]; }

        const int abits = __builtin_bit_cast(int, alpha);
        float s[NT];
#pragma unroll
        for (int i = 0; i < NT; ++i)
            s[i] = __builtin_bit_cast(float, __builtin_amdgcn_readlane(abits, i)) + tt[i];

        // max3 tree over 50 values (exact; order-independent)
        float m[17];
#pragma unroll
        for (int k = 0; k < 16; ++k) m[k] = fmaxf(fmaxf(s[3 * k], s[3 * k + 1]), s[3 * k + 2]);
        m[16] = fmaxf(s[48], s[49]);
        float n[6];
#pragma unroll
        for (int k = 0; k < 5; ++k) n[k] = fmaxf(fmaxf(m[3 * k], m[3 * k + 1]), m[3 * k + 2]);
        n[5] = fmaxf(m[15], m[16]);
        float q0 = fmaxf(fmaxf(n[0], n[1]), n[2]);
        float q1 = fmaxf(fmaxf(n[3], n[4]), n[5]);
        float bv = fmaxf(q0, q1);

        wsb[(size_t)pos * 64] = bv;
        alpha = bv + f;
    }

    // ---- best last tag ----
    float v = alpha + trans[jc * TT + STOP_TAG];
    if (j >= NT) v = -3.0e38f;
    int idx = j < NT ? j : 0;
    for (int off = 32; off; off >>= 1) {
        float vo = __shfl_xor(v, off, 64);
        int   io = __shfl_xor(idx, off, 64);
        if (vo > v || (vo == v && io < idx)) { v = vo; idx = io; }
    }

    __syncthreads();   // trans_lds staged (single wave; cheap)

    // ---- traceback by value matching ----
    int ptr = idx;
    int* ob = out + (size_t)b * SS;
    ob[len - 1] = ptr;                       // all lanes, same addr+value: ok

    const float* wsr = ws + ((size_t)b * SS) * 64;        // + r*64 + j
    const float* fbase = feats + ((size_t)b * SS) * TT;   // + r*TT + jc

    // prefetch slots: slot k holds row (pos-1-k), clamped
    float bvs[4], fs[4];
    float bv_cur;
    {
        int r0 = len - 1;
        bv_cur = wsr[(size_t)r0 * 64 + j];
#pragma unroll
        for (int k = 0; k < 4; ++k) {
            int r = len - 2 - k; int rc = r < 0 ? 0 : r;
            bvs[k] = wsr[(size_t)rc * 64 + j];
            fs[k]  = fbase[(size_t)rc * TT + jc];
        }
    }

    int pos = len - 1;

#define TB_STEP(k)                                                              \
    {                                                                           \
        float bv_prev = bvs[k];                                                 \
        float alpha_prev = bv_prev + fs[k];                                     \
        float cand = alpha_prev + trans_lds[jr + ptr];                          \
        float candm = (j < NT) ? cand : -3.0e38f;                               \
        float tgt = __builtin_bit_cast(float,                                   \
            __builtin_amdgcn_readlane(__builtin_bit_cast(int, bv_cur), ptr));   \
        unsigned long long bm = __ballot(candm == tgt);                         \
        ptr = __ffsll(bm) - 1;                                                  \
        --pos;                                                                  \
        ob[pos] = ptr;                                                          \
        bv_cur = bv_prev;                                                       \
        int rc = pos - 4; rc = rc < 0 ? 0 : rc;                                 \
        bvs[k] = wsr[(size_t)rc * 64 + j];                                      \
        fs[k]  = fbase[(size_t)rc * TT + jc];                                   \
    }

    while (pos >= 4) {
        TB_STEP(0) TB_STEP(1) TB_STEP(2) TB_STEP(3)
    }
#pragma unroll
    for (int k = 0; k < 3; ++k) {
        if (pos >= 1) TB_STEP(k)
    }
#undef TB_STEP

    // zero-fill positions >= len
    for (int p = len + j; p < SS; p += 64) ob[p] = 0;
}

// ---------------- fallback (round-2 proven kernel) --------------------------
__global__ __launch_bounds__(64, 1) void crf_viterbi(
    const float* __restrict__ feats,
    const void*  __restrict__ mask,
    const float* __restrict__ trans,
    int* __restrict__ out)
{
    __shared__ unsigned char bp_sh[SS * BPSTR];

    const int b = blockIdx.x;
    const int j = threadIdx.x;
    const int jc = j < NT ? j : NT - 1;

    const int len = seq_len(mask, b, j);

    float tt[NT];
#pragma unroll
    for (int i = 0; i < NT; ++i) tt[i] = trans[i * TT + j];

    const float* fp = feats + ((size_t)b * SS) * TT + jc;
    float alpha = trans[START_TAG * TT + jc] + fp[0];
    float fnext = fp[TT];

    for (int pos = 1; pos < len; ++pos) {
        const float f = fnext;
        { int np = pos + 1 < SS ? pos + 1 : SS - 1; fnext = fp[(size_t)np * TT]; }

        float best[4] = { -3.0e38f, -3.0e38f, -3.0e38f, -3.0e38f };
        int   bidx[4] = { 0, 0, 0, 0 };
        const int abits = __builtin_bit_cast(int, alpha);
#pragma unroll
        for (int i = 0; i < NT; ++i) {
            int ab = __builtin_amdgcn_readlane(abits, i);
            float s = __builtin_bit_cast(float, ab) + tt[i];
            const int c = i & 3;
            if (s > best[c]) { best[c] = s; bidx[c] = i; }
        }
        float bv = best[0]; int bi = bidx[0];
        if (best[1] > bv || (best[1] == bv && bidx[1] < bi)) { bv = best[1]; bi = bidx[1]; }
        if (best[2] > bv || (best[2] == bv && bidx[2] < bi)) { bv = best[2]; bi = bidx[2]; }
        if (best[3] > bv || (best[3] == bv && bidx[3] < bi)) { bv = best[3]; bi = bidx[3]; }

        alpha = bv + f;
        bp_sh[pos * BPSTR + j] = (unsigned char)bi;
    }

    float v = alpha + trans[jc * TT + STOP_TAG];
    if (j >= NT) v = -3.0e38f;
    int idx = j < NT ? j : 0;
    for (int off = 32; off; off >>= 1) {
        float vo = __shfl_xor(v, off, 64);
        int   io = __shfl_xor(idx, off, 64);
        if (vo > v || (vo == v && io < idx)) { v = vo; idx = io; }
    }

    __syncthreads();

    int ptr = idx;
    int* ob = out + (size_t)b * SS;
    for (int pos = len - 1; pos >= 1; --pos) {
        if (j == 0) ob[pos] = ptr;
        ptr = (int)bp_sh[pos * BPSTR + ptr];
    }
    if (j == 0) ob[0] = ptr;

    for (int p = len + j; p < SS; p += 64) ob[p] = 0;
}

extern "C" void kernel_launch(void* const* d_in, const int* in_sizes, int n_in,
                              void* d_out, int out_size, void* d_ws, size_t ws_size,
                              hipStream_t stream) {
    const float* feats = (const float*)d_in[0];
    const void*  mask  = d_in[1];
    // d_in[2] = tags, unused
    const float* trans = (const float*)d_in[3];
    int* out = (int*)d_out;

    const size_t need = (size_t)BB * SS * 64 * sizeof(float);   // 128 MiB
    if (ws_size >= need) {
        crf_viterbi_fast<<<dim3(BB), dim3(64), 0, stream>>>(feats, mask, trans,
                                                            (float*)d_ws, out);
    } else {
        crf_viterbi<<<dim3(BB), dim3(64), 0, stream>>>(feats, mask, trans, out);
    }
}

// Round 5
// 197.776 us; speedup vs baseline: 2.0250x; 1.3380x over previous
//
#include <hip/hip_runtime.h>

#define TT 52          // tag count incl START/STOP
#define NT 50          // normal tags
#define START_TAG 50
#define STOP_TAG 51
#define BB 1024
#define SS 512
#define BPSTR 64       // fallback kernel LDS bp row stride

__device__ __forceinline__ int seq_len(const void* mask, int b, int j) {
    int cnt = 0;
    const unsigned* w = (const unsigned*)mask;
    unsigned w0 = w[0];
    unsigned w1 = w[1];
    if (w0 == 0x01010101u) {                       // bool / uint8
        const unsigned char* m = (const unsigned char*)mask + (size_t)b * SS;
        for (int k = j; k < SS; k += 64) cnt += (m[k] != 0);
    } else if (w0 == 0x3f800000u) {                // float32
        const float* m = (const float*)mask + (size_t)b * SS;
        for (int k = j; k < SS; k += 64) cnt += (m[k] != 0.f);
    } else if (w1 == 1u) {                         // int32
        const int* m = (const int*)mask + (size_t)b * SS;
        for (int k = j; k < SS; k += 64) cnt += (m[k] != 0);
    } else {                                       // int64
        const long long* m = (const long long*)mask + (size_t)b * SS;
        for (int k = j; k < SS; k += 64) cnt += (m[k] != 0);
    }
    for (int off = 32; off; off >>= 1) cnt += __shfl_xor(cnt, off, 64);
    return cnt > 0 ? cnt : 1;
}

// One DP step: alpha -> bv (max over candidates) -> store bv -> alpha = bv + f
// Bit-identical math to reference: s[i] = alpha[i] + tt[i] (same f32 add), max
// tree is order-independent (exact max), alpha = bv + f same rounding.
#define DP_STEP(FREG, POSV)                                                       \
    {                                                                             \
        const int abits_ = __builtin_bit_cast(int, alpha);                        \
        float s_[NT];                                                             \
        _Pragma("unroll")                                                         \
        for (int i_ = 0; i_ < NT; ++i_)                                           \
            s_[i_] = __builtin_bit_cast(float,                                    \
                         __builtin_amdgcn_readlane(abits_, i_)) + tt[i_];         \
        float m_[17];                                                             \
        _Pragma("unroll")                                                         \
        for (int k_ = 0; k_ < 16; ++k_)                                           \
            m_[k_] = fmaxf(fmaxf(s_[3 * k_], s_[3 * k_ + 1]), s_[3 * k_ + 2]);    \
        m_[16] = fmaxf(s_[48], s_[49]);                                           \
        float n_[6];                                                              \
        _Pragma("unroll")                                                         \
        for (int k_ = 0; k_ < 5; ++k_)                                            \
            n_[k_] = fmaxf(fmaxf(m_[3 * k_], m_[3 * k_ + 1]), m_[3 * k_ + 2]);    \
        n_[5] = fmaxf(m_[15], m_[16]);                                            \
        float q0_ = fmaxf(fmaxf(n_[0], n_[1]), n_[2]);                            \
        float q1_ = fmaxf(fmaxf(n_[3], n_[4]), n_[5]);                            \
        float bv_ = fmaxf(q0_, q1_);                                              \
        wsb[(size_t)(POSV) * 64] = bv_;                                           \
        alpha = bv_ + (FREG);                                                     \
    }

// clamped feats load for lane's own tag (jc) at position p
#define FLD(P) fp[(size_t)((P) < SS ? (P) : SS - 1) * TT]

// ---------------- fast kernel: no per-step argmax; value-match traceback ----
__global__ __launch_bounds__(64, 1) void crf_viterbi_fast(
    const float* __restrict__ feats,   // [B,S,T]
    const void*  __restrict__ mask,    // [B,S]
    const float* __restrict__ trans,   // [T,T]
    float* __restrict__ ws,            // [B,S,64] bv history (128 MiB)
    int* __restrict__ out)             // [B,S]
{
    __shared__ float trans_lds[64 * 53];   // [row i][col c], 53-padded

    const int b = blockIdx.x;
    const int j = threadIdx.x;
    const int jc = j < NT ? j : NT - 1;
    const int jr = j * 53;

    // stage trans rows into LDS; rows >= NT get -inf sentinel
    for (int k = j; k < 64 * 53; k += 64) {
        int r = k / 53, c = k - r * 53;
        float v = -3.0e38f;
        if (r < NT && c < TT) v = trans[r * TT + c];
        trans_lds[k] = v;
    }

    const int len = seq_len(mask, b, j);

    // transition column trans[0..49][j] into registers
    float tt[NT];
#pragma unroll
    for (int i = 0; i < NT; ++i) tt[i] = trans[i * TT + j];

    // init (pos 0): alpha0 = bv0 + f0 with bv0 = trans[START][j]
    const float* fp = feats + ((size_t)b * SS) * TT + jc;
    float* wsb = ws + ((size_t)b * SS) * 64 + j;
    const float bv0 = trans[START_TAG * TT + jc];
    float alpha = bv0 + fp[0];
    wsb[0] = bv0;

    // ---- forward with 8-deep feats prefetch (two named 4-reg groups) ----
    // Invariant at top of each iteration: fA = f[pos..pos+3], fB = f[pos+4..pos+7]
    float fA0 = FLD(1), fA1 = FLD(2), fA2 = FLD(3), fA3 = FLD(4);
    float fB0 = FLD(5), fB1 = FLD(6), fB2 = FLD(7), fB3 = FLD(8);

    int pos = 1;
    for (; pos + 7 < len; pos += 8) {
        DP_STEP(fA0, pos + 0)
        DP_STEP(fA1, pos + 1)
        DP_STEP(fA2, pos + 2)
        DP_STEP(fA3, pos + 3)
        fA0 = FLD(pos + 8);  fA1 = FLD(pos + 9);    // next iter's f[pos'..pos'+3]
        fA2 = FLD(pos + 10); fA3 = FLD(pos + 11);
        DP_STEP(fB0, pos + 4)
        DP_STEP(fB1, pos + 5)
        DP_STEP(fB2, pos + 6)
        DP_STEP(fB3, pos + 7)
        fB0 = FLD(pos + 12); fB1 = FLD(pos + 13);   // next iter's f[pos'+4..pos'+7]
        fB2 = FLD(pos + 14); fB3 = FLD(pos + 15);
    }
    // tail: fA = f[pos..pos+3], fB = f[pos+4..pos+7]; up to 7 steps remain
    if (pos < len) { DP_STEP(fA0, pos) ++pos; }
    if (pos < len) { DP_STEP(fA1, pos) ++pos; }
    if (pos < len) { DP_STEP(fA2, pos) ++pos; }
    if (pos < len) { DP_STEP(fA3, pos) ++pos; }
    if (pos < len) { DP_STEP(fB0, pos) ++pos; }
    if (pos < len) { DP_STEP(fB1, pos) ++pos; }
    if (pos < len) { DP_STEP(fB2, pos) ++pos; }

    // ---- best last tag ----
    float v = alpha + trans[jc * TT + STOP_TAG];
    if (j >= NT) v = -3.0e38f;
    int idx = j < NT ? j : 0;
    for (int off = 32; off; off >>= 1) {
        float vo = __shfl_xor(v, off, 64);
        int   io = __shfl_xor(idx, off, 64);
        if (vo > v || (vo == v && io < idx)) { v = vo; idx = io; }
    }

    __syncthreads();   // trans_lds staged (single wave; cheap)

    // ---- traceback by value matching ----
    int ptr = idx;
    int* ob = out + (size_t)b * SS;
    ob[len - 1] = ptr;

    const float* wsr = ws + ((size_t)b * SS) * 64;        // + r*64 + j
    const float* fbase = feats + ((size_t)b * SS) * TT;   // + r*TT + jc

    float bvs[4], fs[4];
    float bv_cur;
    {
        int r0 = len - 1;
        bv_cur = wsr[(size_t)r0 * 64 + j];
#pragma unroll
        for (int k = 0; k < 4; ++k) {
            int r = len - 2 - k; int rc = r < 0 ? 0 : r;
            bvs[k] = wsr[(size_t)rc * 64 + j];
            fs[k]  = fbase[(size_t)rc * TT + jc];
        }
    }

    int tpos = len - 1;

#define TB_STEP(k)                                                              \
    {                                                                           \
        float bv_prev = bvs[k];                                                 \
        float alpha_prev = bv_prev + fs[k];                                     \
        float cand = alpha_prev + trans_lds[jr + ptr];                          \
        float candm = (j < NT) ? cand : -3.0e38f;                               \
        float tgt = __builtin_bit_cast(float,                                   \
            __builtin_amdgcn_readlane(__builtin_bit_cast(int, bv_cur), ptr));   \
        unsigned long long bm = __ballot(candm == tgt);                         \
        ptr = __ffsll(bm) - 1;                                                  \
        --tpos;                                                                 \
        ob[tpos] = ptr;                                                         \
        bv_cur = bv_prev;                                                       \
        int rc = tpos - 4; rc = rc < 0 ? 0 : rc;                                \
        bvs[k] = wsr[(size_t)rc * 64 + j];                                      \
        fs[k]  = fbase[(size_t)rc * TT + jc];                                   \
    }

    while (tpos >= 4) {
        TB_STEP(0) TB_STEP(1) TB_STEP(2) TB_STEP(3)
    }
#pragma unroll
    for (int k = 0; k < 3; ++k) {
        if (tpos >= 1) TB_STEP(k)
    }
#undef TB_STEP

    // zero-fill positions >= len
    for (int p = len + j; p < SS; p += 64) ob[p] = 0;
}

// ---------------- fallback (round-2 proven kernel, no workspace) ------------
__global__ __launch_bounds__(64, 1) void crf_viterbi(
    const float* __restrict__ feats,
    const void*  __restrict__ mask,
    const float* __restrict__ trans,
    int* __restrict__ out)
{
    __shared__ unsigned char bp_sh[SS * BPSTR];

    const int b = blockIdx.x;
    const int j = threadIdx.x;
    const int jc = j < NT ? j : NT - 1;

    const int len = seq_len(mask, b, j);

    float tt[NT];
#pragma unroll
    for (int i = 0; i < NT; ++i) tt[i] = trans[i * TT + j];

    const float* fp = feats + ((size_t)b * SS) * TT + jc;
    float alpha = trans[START_TAG * TT + jc] + fp[0];
    float fnext = fp[TT];

    for (int pos = 1; pos < len; ++pos) {
        const float f = fnext;
        { int np = pos + 1 < SS ? pos + 1 : SS - 1; fnext = fp[(size_t)np * TT]; }

        float best[4] = { -3.0e38f, -3.0e38f, -3.0e38f, -3.0e38f };
        int   bidx[4] = { 0, 0, 0, 0 };
        const int abits = __builtin_bit_cast(int, alpha);
#pragma unroll
        for (int i = 0; i < NT; ++i) {
            int ab = __builtin_amdgcn_readlane(abits, i);
            float s = __builtin_bit_cast(float, ab) + tt[i];
            const int c = i & 3;
            if (s > best[c]) { best[c] = s; bidx[c] = i; }
        }
        float bv = best[0]; int bi = bidx[0];
        if (best[1] > bv || (best[1] == bv && bidx[1] < bi)) { bv = best[1]; bi = bidx[1]; }
        if (best[2] > bv || (best[2] == bv && bidx[2] < bi)) { bv = best[2]; bi = bidx[2]; }
        if (best[3] > bv || (best[3] == bv && bidx[3] < bi)) { bv = best[3]; bi = bidx[3]; }

        alpha = bv + f;
        bp_sh[pos * BPSTR + j] = (unsigned char)bi;
    }

    float v = alpha + trans[jc * TT + STOP_TAG];
    if (j >= NT) v = -3.0e38f;
    int idx = j < NT ? j : 0;
    for (int off = 32; off; off >>= 1) {
        float vo = __shfl_xor(v, off, 64);
        int   io = __shfl_xor(idx, off, 64);
        if (vo > v || (vo == v && io < idx)) { v = vo; idx = io; }
    }

    __syncthreads();

    int ptr = idx;
    int* ob = out + (size_t)b * SS;
    for (int pos = len - 1; pos >= 1; --pos) {
        if (j == 0) ob[pos] = ptr;
        ptr = (int)bp_sh[pos * BPSTR + ptr];
    }
    if (j == 0) ob[0] = ptr;

    for (int p = len + j; p < SS; p += 64) ob[p] = 0;
}

extern "C" void kernel_launch(void* const* d_in, const int* in_sizes, int n_in,
                              void* d_out, int out_size, void* d_ws, size_t ws_size,
                              hipStream_t stream) {
    const float* feats = (const float*)d_in[0];
    const void*  mask  = d_in[1];
    // d_in[2] = tags, unused
    const float* trans = (const float*)d_in[3];
    int* out = (int*)d_out;

    const size_t need = (size_t)BB * SS * 64 * sizeof(float);   // 128 MiB
    if (ws_size >= need) {
        crf_viterbi_fast<<<dim3(BB), dim3(64), 0, stream>>>(feats, mask, trans,
                                                            (float*)d_ws, out);
    } else {
        crf_viterbi<<<dim3(BB), dim3(64), 0, stream>>>(feats, mask, trans, out);
    }
}